// Round 1
// baseline (85.185 us; speedup 1.0000x reference)
//
#include <hip/hip_runtime.h>

// 10-qubit circuit: 10x Rot(phi,theta,omega) + CNOT ring + <X>,<Y>,<Z> on wire 0.
//
// Circuit = D_omega * RY_layer * D_phi on a REAL input. State = two real vectors
// evolved by the same real RY layer -> amplitudes as v2f, math as v_pk_fma_f32.
//
// R7: ZERO-DS kernel. R6 used ~70 DS-pipe ops/lane (32 ds_swizzle for xor16,
// 32 ds_bpermute for xor32, 6 in the reduction). The DS pipe is per-CU and
// shared by all 4 SIMDs' resident waves, which cluster into the same xgate
// phases -> serialization. gfx950's v_permlane16/32_swap_b32 do the same
// lane exchange on the full-rate VALU pipe:
//   permlane16_swap(x,x) -> (rows {0,0,2,2}, rows {1,1,3,3})
//   permlane32_swap(x,x) -> (lo|lo, hi|hi)
// so partner(lane^16) = (lane&16) ? r.x : r.y   (1 permlane + 1 cndmask).
//
// Layout (validated R4: DS-pipe model, R5: packed fp32): one wave per state;
// lane holds 16 complex amps, slots s = h*4+q, idx = h*256 + lane*4 + q.
//   slot bit0=wire9, bit1=wire8, bit2=wire1, bit3=wire0  (in-register gates)
//   lane bit l = wire 7-l                                 (cross-lane gates)
// Measurement partner idx^0x300 = slot^12 (in-register, no shuffles).
// Cross-lane masks 1,2,4,8 via DPP (VALU pipe); 16,32 via permlane_swap (VALU).

typedef float v2f __attribute__((ext_vector_type(2)));
typedef unsigned int v2u __attribute__((ext_vector_type(2)));

__device__ __forceinline__ v2f psplat(float k) { v2f r; r.x = k; r.y = k; return r; }
__device__ __forceinline__ v2f pfma(float k, v2f a, v2f b) {
    return __builtin_elementwise_fma(psplat(k), a, b);  // v_pk_fma_f32
}

template <int CTRL>
__device__ __forceinline__ float dppf(float x) {
    return __int_as_float(__builtin_amdgcn_update_dpp(
        __float_as_int(x), __float_as_int(x), CTRL, 0xF, 0xF, true));
}

template <int MASK>
__device__ __forceinline__ float lxor(float x) {
    if constexpr (MASK == 1)  return dppf<0xB1>(x);                   // quad_perm [1,0,3,2]
    else if constexpr (MASK == 2)  return dppf<0x4E>(x);              // quad_perm [2,3,0,1]
    else if constexpr (MASK == 4)  return dppf<0x141>(dppf<0x1B>(x)); // half_mirror o xor3
    else if constexpr (MASK == 8)  return dppf<0x128>(x);             // row_ror:8
    else if constexpr (MASK == 16)
        return __int_as_float(__builtin_amdgcn_ds_swizzle(__float_as_int(x), 0x401F));
    else return __shfl_xor(x, MASK, 64);
}

// partner value x[lane^MASK]; hi = (lane & MASK) != 0 (only used for 16/32)
template <int MASK>
__device__ __forceinline__ float xpartner(float x, bool hi) {
    if constexpr (MASK == 16) {
#if __has_builtin(__builtin_amdgcn_permlane16_swap)
        v2u r = __builtin_amdgcn_permlane16_swap(__float_as_uint(x), __float_as_uint(x),
                                                 false, false);
        // r.x = {row0,row0,row2,row2}, r.y = {row1,row1,row3,row3}
        return __uint_as_float(hi ? r.x : r.y);
#else
        (void)hi;
        return lxor<16>(x);
#endif
    } else if constexpr (MASK == 32) {
#if __has_builtin(__builtin_amdgcn_permlane32_swap)
        v2u r = __builtin_amdgcn_permlane32_swap(__float_as_uint(x), __float_as_uint(x),
                                                 false, false);
        // r.x = {lo,lo}, r.y = {hi,hi}
        return __uint_as_float(hi ? r.x : r.y);
#else
        (void)hi;
        return lxor<32>(x);
#endif
    } else {
        (void)hi;
        return lxor<MASK>(x);
    }
}

#define RLF(v, l) __int_as_float(__builtin_amdgcn_readlane(__float_as_int(v), (l)))

__device__ __forceinline__ void rgate(v2f (&amp)[16], int bit, float c, float s) {
#pragma unroll
    for (int s0 = 0; s0 < 16; s0++) {
        if (s0 & bit) continue;
        int s1 = s0 | bit;
        v2f a0 = amp[s0], a1 = amp[s1];
        amp[s0] = pfma(-s, a1, psplat(c) * a0);
        amp[s1] = pfma( s, a0, psplat(c) * a1);
    }
}

template <int MASK>
__device__ __forceinline__ void xgate(v2f (&amp)[16], float c, float ss, bool hi) {
#pragma unroll
    for (int r = 0; r < 16; r++) {
        v2f p;
        p.x = xpartner<MASK>(amp[r].x, hi);
        p.y = xpartner<MASK>(amp[r].y, hi);
        amp[r] = pfma(ss, p, psplat(c) * amp[r]);
    }
}

__global__ __launch_bounds__(256) void qk_sim(const float* __restrict__ x,
                                              const float* __restrict__ w,
                                              float* __restrict__ out,
                                              int nstates) {
    int wave = (int)((blockIdx.x * blockDim.x + threadIdx.x) >> 6);
    int lane = threadIdx.x & 63;

    // ---- issue the 4 state loads first: MLP ahead of the trig chain ----
    const float4* rowx = (const float4*)(x + (size_t)wave * 1024);
    float4 vv[4];
#pragma unroll
    for (int h = 0; h < 4; h++) vv[h] = rowx[h * 64 + lane];

    // ---- theta cos/sin: lanes 0..9 compute, broadcast via v_readlane ----
    int wi = (lane < 10) ? lane : 0;
    float thh = 0.5f * w[3 * wi + 1];
    float vc = __cosf(thh), vs = __sinf(thh);
    float c0 = RLF(vc, 0), s0 = RLF(vs, 0);
    float c1 = RLF(vc, 1), s1 = RLF(vs, 1);
    float c2 = RLF(vc, 2), s2 = RLF(vs, 2);
    float c3 = RLF(vc, 3), s3 = RLF(vs, 3);
    float c4 = RLF(vc, 4), s4 = RLF(vs, 4);
    float c5 = RLF(vc, 5), s5 = RLF(vs, 5);
    float c6 = RLF(vc, 6), s6 = RLF(vs, 6);
    float c7 = RLF(vc, 7), s7 = RLF(vs, 7);
    float c8 = RLF(vc, 8), s8 = RLF(vs, 8);
    float c9 = RLF(vc, 9), s9 = RLF(vs, 9);

    // ---- omega fold (uniform): d0 = w0+w1 omegas (h=0), d1 = w0-w1 (h=1) ----
    float om0 = w[2], om1 = w[5];
    float cD0 = __cosf(om0 + om1), sD0 = __sinf(om0 + om1);
    float cD1 = __cosf(om0 - om1), sD1 = __sinf(om0 - om1);

    // ---- phase angles: alpha(idx) = aL(lane) + aH(h) + aQ(q) ----
    // lane bit l -> wire 7-l (phi = w[3*(7-l)]); h: bit1->wire0, bit0->wire1;
    // q: bit1->wire8, bit0->wire9.
    float aL = 0.f;
    if (lane & 1)  aL += w[21];
    if (lane & 2)  aL += w[18];
    if (lane & 4)  aL += w[15];
    if (lane & 8)  aL += w[12];
    if (lane & 16) aL += w[9];
    if (lane & 32) aL += w[6];
    float pH = w[0], pHb = w[3];   // wire0, wire1
    float pQ = w[24], pQb = w[27]; // wire8, wire9
    float aH[4] = {0.f, pHb, pH, pH + pHb};
    float aQ[4] = {0.f, pQb, pQ, pQ + pQb};

    // ---- D_phi: amp[s] = x[idx] * e^{i alpha} ----
    v2f amp[16];
#pragma unroll
    for (int h = 0; h < 4; h++) {
        float base = aL + aH[h];
        float xv[4] = {vv[h].x, vv[h].y, vv[h].z, vv[h].w};
#pragma unroll
        for (int q = 0; q < 4; q++) {
            float a = base + aQ[q];
            v2f e; e.x = __cosf(a); e.y = __sinf(a);
            amp[h * 4 + q] = psplat(xv[q]) * e;
        }
    }

    // ---- in-register RY: slot bit0=wire9, bit1=wire8, bit2=wire1, bit3=wire0 ----
    rgate(amp, 1, c9, s9);
    rgate(amp, 2, c8, s8);
    rgate(amp, 4, c1, s1);
    rgate(amp, 8, c0, s0);

    // ---- cross-lane RY: lane bit l -> wire 7-l ; bit=0: c*m - s*p, bit=1: +s*p ----
    bool h16 = (lane & 16) != 0;
    bool h32 = (lane & 32) != 0;
    xgate<1> (amp, c7, (lane & 1) ? s7 : -s7, false);
    xgate<2> (amp, c6, (lane & 2) ? s6 : -s6, false);
    xgate<4> (amp, c5, (lane & 4) ? s5 : -s5, false);
    xgate<8> (amp, c4, (lane & 8) ? s4 : -s4, false);
    xgate<16>(amp, c3, h16 ? s3 : -s3, h16);
    xgate<32>(amp, c2, h32 ? s2 : -s2, h32);

    // ---- measurement: CNOT ring + D_omega folded; partner = slot^12 ----
    float ex2 = 0.f, ey2 = 0.f;
    v2f ezv = psplat(0.f);
#pragma unroll
    for (int h = 0; h < 2; h++) {
        float cD = h ? cD1 : cD0;
        float sD = h ? sD1 : sD0;
#pragma unroll
        for (int q = 0; q < 4; q++) {
            int s  = h * 4 + q;
            int sp = s ^ 12;
            v2f m = amp[s], p = amp[sp];
            float cr = m.x * p.x + m.y * p.y;   // Re(conj(m)*p)
            float ci = m.x * p.y - m.y * p.x;   // Im(conj(m)*p)
            ex2 += cD * cr - sD * ci;
            float t = cD * ci + sD * cr;
            if ((h ^ (__popc(q) & 1)) & 1) ey2 -= t; else ey2 += t;
        }
    }
#pragma unroll
    for (int s = 0; s < 16; s++) {
        v2f n = amp[s] * amp[s];
        if ((((s >> 2) & 1) ^ (__popc(s & 3) & 1)) & 1) ezv -= n; else ezv += n;
    }
    float psgn = (__popc(lane) & 1) ? -1.f : 1.f;
    v2f exy;
    exy.x = 2.f * ex2;
    exy.y = 2.f * psgn * ey2;
    float ez = psgn * (ezv.x + ezv.y);

    // ---- wave reduction: DPP for 1,2,4,8; permlane_swap for 16,32 ----
#define RED(M, HI) { v2f o; o.x = xpartner<M>(exy.x, HI); o.y = xpartner<M>(exy.y, HI); \
                     exy += o; ez += xpartner<M>(ez, HI); }
    RED(1, false) RED(2, false) RED(4, false) RED(8, false) RED(16, h16) RED(32, h32)
#undef RED

    if (lane == 0) {
        float* o = out + 3 * (size_t)wave;
        o[0] = exy.x; o[1] = exy.y; o[2] = ez;
    }
}

extern "C" void kernel_launch(void* const* d_in, const int* in_sizes, int n_in,
                              void* d_out, int out_size, void* d_ws, size_t ws_size,
                              hipStream_t stream) {
    const float* patch   = (const float*)d_in[0];
    const float* weights = (const float*)d_in[1];
    float* out = (float*)d_out;

    int nstates = in_sizes[0] / 1024;  // 8192

    int nblocks = nstates / 4;  // 4 waves (256 threads) per block, grid exact
    qk_sim<<<nblocks, 256, 0, stream>>>(patch, weights, out, nstates);
}